// Round 9
// baseline (671.298 us; speedup 1.0000x reference)
//
#include <hip/hip_runtime.h>

// ===========================================================================
// ViewGCNEncoder r9. Proven dtype model: f32 in / f32 out / bf16-graded,
// masks sniffed. r8->r9: (1) SpMM 64-col chunking for L2 locality (r8 FETCH
// showed 50% L2 miss on gathers), (2) packed (col,val) edge stream, (3) GEMM
// A-prefetch pipeline, (4) parallel scan + fused small kernels.
// Workspace ~84 MB (<=110 MB proven safe in r3).
// ===========================================================================

typedef unsigned short ushort_t;
typedef __attribute__((ext_vector_type(8))) short bf16x8;   // 8 bf16 = 4 VGPRs
typedef __attribute__((ext_vector_type(4))) float f32x4;
typedef __attribute__((ext_vector_type(2))) unsigned int u32x2;

__device__ __forceinline__ float bf2f(ushort_t u) {
  return __uint_as_float(((unsigned int)u) << 16);
}
__device__ __forceinline__ ushort_t f2bf(float f) {
  unsigned int u = __float_as_uint(f);
  return (ushort_t)((u + 0x7FFFu + ((u >> 16) & 1u)) >> 16);  // RNE
}
__device__ __forceinline__ float read_f(const void* p, int fm, size_t i) {
  return fm ? bf2f(((const ushort_t*)p)[i]) : ((const float*)p)[i];
}

// ---------------- fused dtype sniff: block 0 = float(x), 1/2 = masks -------
__global__ void sniff_all_kernel(const void* __restrict__ x,
                                 const void* __restrict__ m1,
                                 const void* __restrict__ m2,
                                 int* __restrict__ modes) {
  if (blockIdx.x == 0) {
    __shared__ int bfok;
    if (threadIdx.x == 0) bfok = 1;
    __syncthreads();
    for (int i = threadIdx.x; i < 8192; i += blockDim.x) {
      ushort_t h = ((const ushort_t*)x)[i];
      int e = (h >> 7) & 0xFF;
      if (!(h == 0 || (e >= 95 && e <= 133))) atomicAnd(&bfok, 0);
    }
    __syncthreads();
    if (threadIdx.x == 0) modes[0] = bfok;   // 1=bf16, 0=f32
  } else {
    const void* p = (blockIdx.x == 1) ? m1 : m2;
    __shared__ int ok[4];  // [i32, f32, bf16, u8]
    if (threadIdx.x < 4) ok[threadIdx.x] = 1;
    __syncthreads();
    for (int i = threadIdx.x; i < 4096; i += blockDim.x) {
      unsigned int w = ((const unsigned int*)p)[i];
      if (!(w == 0u || w == 1u)) atomicAnd(&ok[0], 0);
      if (!(w == 0u || w == 0x3F800000u)) atomicAnd(&ok[1], 0);
      unsigned int h16 = w >> 16, l16 = w & 0xFFFFu;
      if (!((h16 == 0u || h16 == 0x3F80u) && (l16 == 0u || l16 == 0x3F80u)))
        atomicAnd(&ok[2], 0);
      if (((w | (w >> 8) | (w >> 16) | (w >> 24)) & 0xFEu) != 0u) atomicAnd(&ok[3], 0);
    }
    __syncthreads();
    if (threadIdx.x == 0)
      modes[blockIdx.x] = ok[0] ? 1 : (ok[1] ? 2 : (ok[2] ? 3 : 0));
  }
}

__device__ __forceinline__ bool mask_keep(const void* mask, int mm, size_t o) {
  switch (mm) {
    case 1:  return ((const int*)mask)[o] != 0;
    case 2:  return ((const unsigned int*)mask)[o] != 0u;
    case 3:  return ((const ushort_t*)mask)[o] != 0;
    default: return ((const unsigned char*)mask)[o] != 0;
  }
}

// ---------------- CSR build ----------------
__global__ void hist_kernel(const int* __restrict__ rows, int* __restrict__ cnt, int E) {
  int i = blockIdx.x * blockDim.x + threadIdx.x;
  int stride = gridDim.x * blockDim.x;
  for (; i < E; i += stride) atomicAdd(&cnt[rows[i]], 1);
}

// parallel scan: partials -> top scan -> apply
__global__ void scan_part_kernel(const int* __restrict__ cnt, int* __restrict__ part, int n) {
  __shared__ int s[256];
  int i = blockIdx.x * 256 + threadIdx.x;
  s[threadIdx.x] = (i < n) ? cnt[i] : 0;
  __syncthreads();
  for (int off = 128; off > 0; off >>= 1) {
    if (threadIdx.x < off) s[threadIdx.x] += s[threadIdx.x + off];
    __syncthreads();
  }
  if (threadIdx.x == 0) part[blockIdx.x] = s[0];
}

__global__ __launch_bounds__(1024) void scan_top_kernel(int* __restrict__ part, int P) {
  __shared__ int s[1024];
  int t = threadIdx.x;
  int v = (t < P) ? part[t] : 0;
  s[t] = v;
  __syncthreads();
  for (int off = 1; off < 1024; off <<= 1) {
    int x = s[t];
    int y = (t >= off) ? s[t - off] : 0;
    __syncthreads();
    s[t] = x + y;
    __syncthreads();
  }
  if (t < P) part[t] = s[t] - v;   // exclusive
}

__global__ void scan_apply_kernel(const int* __restrict__ cnt, const int* __restrict__ part,
                                  int* __restrict__ row_start, int n) {
  __shared__ int s[256];
  int base = part[blockIdx.x];
  int i = blockIdx.x * 256 + threadIdx.x;
  int v = (i < n) ? cnt[i] : 0;
  s[threadIdx.x] = v;
  __syncthreads();
  for (int off = 1; off < 256; off <<= 1) {
    int x = s[threadIdx.x];
    int y = (threadIdx.x >= off) ? s[threadIdx.x - off] : 0;
    __syncthreads();
    s[threadIdx.x] = x + y;
    __syncthreads();
  }
  if (i < n) row_start[i] = base + s[threadIdx.x] - v;
  if (i == n - 1) row_start[n] = base + s[threadIdx.x];
}

// scatter: packed (col, val-bits) 8B stream
__global__ void scatter_kernel(const int* __restrict__ rows, const int* __restrict__ cols,
                               const void* __restrict__ vals, const int* __restrict__ fm_p,
                               const int* __restrict__ row_start, int* __restrict__ fill,
                               int2* __restrict__ ecv, int E) {
  int fm = *fm_p;
  int i = blockIdx.x * blockDim.x + threadIdx.x;
  int stride = gridDim.x * blockDim.x;
  for (; i < E; i += stride) {
    int r = rows[i];
    int pos = atomicAdd(&fill[r], 1);
    int idx = row_start[r] + pos;
    ecv[idx] = make_int2(cols[i], __float_as_int(read_f(vals, fm, i)));
  }
}

// ---------------- fused conversions ----------------
// all 3 weights -> hi/lo bf16 (concatenated layout)
__global__ void split_w_all_kernel(const void* __restrict__ W1, const void* __restrict__ W2,
                                   const void* __restrict__ W3, const int* __restrict__ fm_p,
                                   ushort_t* __restrict__ whi, ushort_t* __restrict__ wlo,
                                   int n1, int n2, int n3) {
  int fm = *fm_p;
  int total = n1 + n2 + n3;
  int i = blockIdx.x * blockDim.x + threadIdx.x;
  int stride = gridDim.x * blockDim.x;
  for (; i < total; i += stride) {
    const void* src; int j;
    if (i < n1) { src = W1; j = i; }
    else if (i < n1 + n2) { src = W2; j = i - n1; }
    else { src = W3; j = i - n1 - n2; }
    float v = read_f(src, fm, j);
    ushort_t h = f2bf(v);
    whi[i] = h;
    wlo[i] = f2bf(v - bf2f(h));
  }
}

__global__ void cvt_bias_all_kernel(const void* __restrict__ b1, const void* __restrict__ b2,
                                    const void* __restrict__ b3, const int* __restrict__ fm_p,
                                    float* __restrict__ dst, int n1, int n2, int n3) {
  int fm = *fm_p;
  int i = threadIdx.x + blockIdx.x * blockDim.x;
  int total = n1 + n2 + n3;
  if (i >= total) return;
  const void* src; int j;
  if (i < n1) { src = b1; j = i; }
  else if (i < n1 + n2) { src = b2; j = i - n1; }
  else { src = b3; j = i - n1 - n2; }
  dst[i] = read_f(src, fm, j);
}

// x -> plain bf16, 4 elems/thread
__global__ void cvt_bf16x4_kernel(const void* __restrict__ src, const int* __restrict__ fm_p,
                                  ushort_t* __restrict__ dst, int n4) {
  int fm = *fm_p;
  int i = blockIdx.x * blockDim.x + threadIdx.x;
  int stride = gridDim.x * blockDim.x;
  for (; i < n4; i += stride) {
    if (fm == 0) {
      f32x4 v = ((const f32x4*)src)[i];
      unsigned int lo = (unsigned int)f2bf(v[0]) | ((unsigned int)f2bf(v[1]) << 16);
      unsigned int hi = (unsigned int)f2bf(v[2]) | ((unsigned int)f2bf(v[3]) << 16);
      ((u32x2*)dst)[i] = (u32x2){lo, hi};
    } else {
      ((u32x2*)dst)[i] = ((const u32x2*)src)[i];
    }
  }
}

// ---------------- GEMM v4: W-in-registers + A-prefetch pipeline -------------
// g[m,n] = sum_k A[m,k]*W[n,k] + bias[n].  K = KC*32, nct = Nout/16.
// Wave owns col-tile ct = gw % nct (NW % nct == 0), W hi/lo frags resident.
// Task loop grid-strides over row-tiles; next task's A-frags are issued
// BEFORE the current MFMA block -> A-load latency hidden (r7/r8 lesson).
// Layouts (m89/m91-verified): A lane=A[m=lane&15][k=quad*8+j];
// B = B[k=quad*8+j][n=lane&15] (=W[n][k]); C/D col=lane&15, row=quad*4+reg.
template<int KC>
__global__ __launch_bounds__(256) void gemm_breg_kernel(
    const ushort_t* __restrict__ A,
    const ushort_t* __restrict__ Whi, const ushort_t* __restrict__ Wlo,
    const float* __restrict__ bias, ushort_t* __restrict__ g, int ldg,
    int M, int nct) {
  const int K = KC * 32;
  int wave = threadIdx.x >> 6, lane = threadIdx.x & 63;
  int gw = blockIdx.x * 4 + wave;
  int NW = gridDim.x * 4;
  int mr = lane & 15, quad = lane >> 4;
  int ct = gw % nct;
  int nrt = (M + 15) >> 4;
  int ntasks = nct * nrt;
  if (gw >= ntasks) return;

  bf16x8 wh[KC], wl[KC];
  {
    const ushort_t* wp = Whi + (size_t)(ct * 16 + mr) * K + quad * 8;
    const ushort_t* wq = Wlo + (size_t)(ct * 16 + mr) * K + quad * 8;
#pragma unroll
    for (int kc = 0; kc < KC; ++kc) {
      wh[kc] = *(const bf16x8*)(wp + kc * 32);
      wl[kc] = *(const bf16x8*)(wq + kc * 32);
    }
  }
  int col = ct * 16 + mr;
  float bv = bias[col];

  int task = gw;
  bf16x8 af[KC];
  {
    int m = (task / nct) * 16 + mr; if (m >= M) m = M - 1;
    const ushort_t* ap = A + (size_t)m * K + quad * 8;
#pragma unroll
    for (int kc = 0; kc < KC; ++kc) af[kc] = *(const bf16x8*)(ap + kc * 32);
  }

#pragma unroll 1
  for (;;) {
    int next = task + NW;
    bool has_next = next < ntasks;
    bf16x8 afn[KC];
    if (has_next) {
      int m = (next / nct) * 16 + mr; if (m >= M) m = M - 1;
      const ushort_t* ap = A + (size_t)m * K + quad * 8;
#pragma unroll
      for (int kc = 0; kc < KC; ++kc) afn[kc] = *(const bf16x8*)(ap + kc * 32);
    }

    f32x4 acc[4];
#pragma unroll
    for (int t = 0; t < 4; ++t) acc[t] = (f32x4){0.f, 0.f, 0.f, 0.f};
#pragma unroll
    for (int kc = 0; kc < KC; ++kc) {
      acc[(2 * kc) & 3] = __builtin_amdgcn_mfma_f32_16x16x32_bf16(af[kc], wh[kc], acc[(2 * kc) & 3], 0, 0, 0);
      acc[(2 * kc + 1) & 3] = __builtin_amdgcn_mfma_f32_16x16x32_bf16(af[kc], wl[kc], acc[(2 * kc + 1) & 3], 0, 0, 0);
    }
    int m0 = (task / nct) * 16;
#pragma unroll
    for (int r = 0; r < 4; ++r) {
      int row = m0 + quad * 4 + r;
      float s = ((acc[0][r] + acc[1][r]) + (acc[2][r] + acc[3][r])) + bv;
      if (row < M) g[(size_t)row * ldg + col] = f2bf(s);
    }
    if (!has_next) break;
#pragma unroll
    for (int kc = 0; kc < KC; ++kc) af[kc] = afn[kc];
    task = next;
  }
}

// ---------------- SpMM v5: 64-col chunks for L2 locality --------------------
// out[r, c*64+lane] = sum_e val[e]*G[col[e], c*64+lane].
// chunk = blockIdx/bpc -> co-resident blocks share a 6.4MB slice (vs 25.6MB
// in r8 -> FETCH showed 50% L2 miss). One 128B cache line per edge-gather.
// MODE 1: leaky(0.2)+mask -> bf16.  MODE 0: plain -> f32 (final out).
template<int MODE>
__global__ __launch_bounds__(256) void spmm5_kernel(
    const int* __restrict__ row_start, const int2* __restrict__ ecv,
    const ushort_t* __restrict__ G, int D,
    const void* __restrict__ mask, const int* __restrict__ mmode_p,
    void* __restrict__ outp, int N, int bpc) {
  int wave = threadIdx.x >> 6, lane = threadIdx.x & 63;
  int chunk = blockIdx.x / bpc;
  int rb = blockIdx.x - chunk * bpc;
  int r = rb * 4 + wave;
  if (r >= N) return;
  int f = chunk * 64 + lane;
  int e = row_start[r], e1 = row_start[r + 1];
  float a = 0.f;
  for (; e < e1; e += 8) {
    int idx[8]; float v[8];
#pragma unroll
    for (int j = 0; j < 8; ++j) {
      int ee = e + j;
      bool ok = ee < e1;
      int2 cv = ecv[ok ? ee : e1 - 1];
      idx[j] = cv.x;
      v[j] = ok ? __int_as_float(cv.y) : 0.f;
    }
    ushort_t h[8];
#pragma unroll
    for (int j = 0; j < 8; ++j) h[j] = G[(size_t)idx[j] * D + f];
#pragma unroll
    for (int j = 0; j < 8; ++j) a += v[j] * bf2f(h[j]);
  }
  size_t o = (size_t)r * D + f;
  if (MODE == 1) {
    a = (a >= 0.f) ? a : 0.2f * a;                       // leaky relu 0.2
    a = mask_keep(mask, *mmode_p, o) ? a * 1.25f : 0.f;  // keep = 1/(1-0.2)
    ((ushort_t*)outp)[o] = f2bf(a);
  } else {
    ((float*)outp)[o] = a;                               // final f32 out
  }
}

// ---------------- launch ----------------
extern "C" void kernel_launch(void* const* d_in, const int* in_sizes, int n_in,
                              void* d_out, int out_size, void* d_ws, size_t ws_size,
                              hipStream_t stream) {
  const void* x     = d_in[0];
  const int*  rows  = (const int*)d_in[1];
  const int*  cols  = (const int*)d_in[2];
  const void* vals  = d_in[3];
  const void* W1    = d_in[4];
  const void* b1    = d_in[5];
  const void* W2    = d_in[6];
  const void* b2    = d_in[7];
  const void* W3    = d_in[8];
  const void* b3    = d_in[9];
  const void* mask1 = d_in[10];
  const void* mask2 = d_in[11];

  const int H1  = in_sizes[5];            // 256
  const int H2  = in_sizes[7];            // 128
  const int OUT = in_sizes[9];            // 64
  const int IN  = in_sizes[4] / H1;       // 256
  const int N   = in_sizes[0] / IN;       // 50000
  const int E   = in_sizes[1];            // 800000
  const int W1n = in_sizes[4], W2n = in_sizes[6], W3n = in_sizes[8];

  char* ws = (char*)d_ws;
  size_t off = 0;
  auto alloc = [&](size_t bytes) -> void* {
    void* p = ws + off;
    off = (off + bytes + 255) & ~(size_t)255;
    return p;
  };
  int*      modes     = (int*)alloc(4 * 4);
  int*      row_start = (int*)alloc((size_t)(N + 1) * 4);
  int*      cnt       = (int*)alloc((size_t)N * 4);
  int*      part      = (int*)alloc(1024 * 4);
  int2*     ecv       = (int2*)alloc((size_t)E * 8);
  ushort_t* whi       = (ushort_t*)alloc((size_t)(W1n + W2n + W3n) * 2);
  ushort_t* wlo       = (ushort_t*)alloc((size_t)(W1n + W2n + W3n) * 2);
  float*    biasf     = (float*)alloc((size_t)(H1 + H2 + OUT) * 4);
  ushort_t* bufA      = (ushort_t*)alloc((size_t)N * H1 * 2);   // 25.6 MB
  ushort_t* bufB      = (ushort_t*)alloc((size_t)N * H1 * 2);   // 25.6 MB
  ushort_t* bufC      = (ushort_t*)alloc((size_t)N * H1 * 2);   // 25.6 MB
  // total ~84 MB (<=110 MB proven safe in r3)

  int* fmode = modes;
  int* mm1   = modes + 1;
  int* mm2   = modes + 2;
  ushort_t* w1hi = whi,             *w1lo = wlo;
  ushort_t* w2hi = whi + W1n,       *w2lo = wlo + W1n;
  ushort_t* w3hi = whi + W1n + W2n, *w3lo = wlo + W1n + W2n;

  sniff_all_kernel<<<3, 256, 0, stream>>>(x, mask1, mask2, modes);

  // CSR build with parallel scan
  const int P = (N + 255) / 256;           // 196 partial blocks
  hipMemsetAsync(cnt, 0, (size_t)N * 4, stream);
  hist_kernel<<<1024, 256, 0, stream>>>(rows, cnt, E);
  scan_part_kernel<<<P, 256, 0, stream>>>(cnt, part, N);
  scan_top_kernel<<<1, 1024, 0, stream>>>(part, P);
  scan_apply_kernel<<<P, 256, 0, stream>>>(cnt, part, row_start, N);
  hipMemsetAsync(cnt, 0, (size_t)N * 4, stream);
  scatter_kernel<<<1024, 256, 0, stream>>>(rows, cols, vals, fmode, row_start, cnt, ecv, E);

  // conversions (fused)
  int wtot = W1n + W2n + W3n;
  split_w_all_kernel<<<(wtot + 255) / 256, 256, 0, stream>>>(
      W1, W2, W3, fmode, whi, wlo, W1n, W2n, W3n);
  cvt_bias_all_kernel<<<(H1 + H2 + OUT + 255) / 256, 256, 0, stream>>>(
      b1, b2, b3, fmode, biasf, H1, H2, OUT);
  cvt_bf16x4_kernel<<<2048, 256, 0, stream>>>(x, fmode, bufA, (N * IN) / 4);

  const int GEMM_BLOCKS = 2048;            // 8192 waves; % {16,8,4} == 0
  int bpc = (N + 3) / 4;                   // SpMM blocks per 64-col chunk

  // layer 1: GEMM(IN->H1) -> SpMM(D=256: 4 chunks, act+mask1)
  gemm_breg_kernel<8><<<GEMM_BLOCKS, 256, 0, stream>>>(
      bufA, w1hi, w1lo, biasf, bufB, H1, N, H1 / 16);
  spmm5_kernel<1><<<bpc * (H1 / 64), 256, 0, stream>>>(
      row_start, ecv, bufB, H1, mask1, mm1, bufC, N, bpc);
  // layer 2: GEMM(H1->H2) -> SpMM(D=128: 2 chunks, act+mask2)
  gemm_breg_kernel<8><<<GEMM_BLOCKS, 256, 0, stream>>>(
      bufC, w2hi, w2lo, biasf + H1, bufB, H2, N, H2 / 16);
  spmm5_kernel<1><<<bpc * (H2 / 64), 256, 0, stream>>>(
      row_start, ecv, bufB, H2, mask2, mm2, bufA, N, bpc);
  // layer 3: GEMM(H2->OUT) -> SpMM(D=64: 1 chunk, plain) -> f32 d_out
  gemm_breg_kernel<4><<<GEMM_BLOCKS, 256, 0, stream>>>(
      bufA, w3hi, w3lo, biasf + H1 + H2, bufB, OUT, N, OUT / 16);
  spmm5_kernel<0><<<bpc * (OUT / 64), 256, 0, stream>>>(
      row_start, ecv, bufB, OUT, nullptr, fmode, d_out, N, bpc);
}

// Round 10
// 584.067 us; speedup vs baseline: 1.1494x; 1.1494x over previous
//
#include <hip/hip_runtime.h>

// ===========================================================================
// ViewGCNEncoder r10. Proven dtype model: f32 in / f32 out / bf16-graded,
// masks sniffed. r9->r10: SpMM reverted to wide one-wave-per-row gathers
// (r9's 64-col chunking regressed 84->177 us: same L2 misses, 1/4 the MLP),
// now with packed (col,val) stream + 16-deep gather pipeline. Keeps r9 aux
// (parallel scan, fused conversions, GEMM A-prefetch).
// Workspace ~84 MB (<=110 MB proven safe in r3).
// ===========================================================================

typedef unsigned short ushort_t;
typedef __attribute__((ext_vector_type(8))) short bf16x8;   // 8 bf16 = 4 VGPRs
typedef __attribute__((ext_vector_type(4))) float f32x4;
typedef __attribute__((ext_vector_type(2))) unsigned int u32x2;

__device__ __forceinline__ float bf2f(ushort_t u) {
  return __uint_as_float(((unsigned int)u) << 16);
}
__device__ __forceinline__ ushort_t f2bf(float f) {
  unsigned int u = __float_as_uint(f);
  return (ushort_t)((u + 0x7FFFu + ((u >> 16) & 1u)) >> 16);  // RNE
}
__device__ __forceinline__ float read_f(const void* p, int fm, size_t i) {
  return fm ? bf2f(((const ushort_t*)p)[i]) : ((const float*)p)[i];
}

// ---------------- fused dtype sniff: block 0 = float(x), 1/2 = masks -------
__global__ void sniff_all_kernel(const void* __restrict__ x,
                                 const void* __restrict__ m1,
                                 const void* __restrict__ m2,
                                 int* __restrict__ modes) {
  if (blockIdx.x == 0) {
    __shared__ int bfok;
    if (threadIdx.x == 0) bfok = 1;
    __syncthreads();
    for (int i = threadIdx.x; i < 8192; i += blockDim.x) {
      ushort_t h = ((const ushort_t*)x)[i];
      int e = (h >> 7) & 0xFF;
      if (!(h == 0 || (e >= 95 && e <= 133))) atomicAnd(&bfok, 0);
    }
    __syncthreads();
    if (threadIdx.x == 0) modes[0] = bfok;   // 1=bf16, 0=f32
  } else {
    const void* p = (blockIdx.x == 1) ? m1 : m2;
    __shared__ int ok[4];  // [i32, f32, bf16, u8]
    if (threadIdx.x < 4) ok[threadIdx.x] = 1;
    __syncthreads();
    for (int i = threadIdx.x; i < 4096; i += blockDim.x) {
      unsigned int w = ((const unsigned int*)p)[i];
      if (!(w == 0u || w == 1u)) atomicAnd(&ok[0], 0);
      if (!(w == 0u || w == 0x3F800000u)) atomicAnd(&ok[1], 0);
      unsigned int h16 = w >> 16, l16 = w & 0xFFFFu;
      if (!((h16 == 0u || h16 == 0x3F80u) && (l16 == 0u || l16 == 0x3F80u)))
        atomicAnd(&ok[2], 0);
      if (((w | (w >> 8) | (w >> 16) | (w >> 24)) & 0xFEu) != 0u) atomicAnd(&ok[3], 0);
    }
    __syncthreads();
    if (threadIdx.x == 0)
      modes[blockIdx.x] = ok[0] ? 1 : (ok[1] ? 2 : (ok[2] ? 3 : 0));
  }
}

__device__ __forceinline__ bool mask_keep(const void* mask, int mm, size_t o) {
  switch (mm) {
    case 1:  return ((const int*)mask)[o] != 0;
    case 2:  return ((const unsigned int*)mask)[o] != 0u;
    case 3:  return ((const ushort_t*)mask)[o] != 0;
    default: return ((const unsigned char*)mask)[o] != 0;
  }
}

// ---------------- CSR build ----------------
__global__ void hist_kernel(const int* __restrict__ rows, int* __restrict__ cnt, int E) {
  int i = blockIdx.x * blockDim.x + threadIdx.x;
  int stride = gridDim.x * blockDim.x;
  for (; i < E; i += stride) atomicAdd(&cnt[rows[i]], 1);
}

__global__ void scan_part_kernel(const int* __restrict__ cnt, int* __restrict__ part, int n) {
  __shared__ int s[256];
  int i = blockIdx.x * 256 + threadIdx.x;
  s[threadIdx.x] = (i < n) ? cnt[i] : 0;
  __syncthreads();
  for (int off = 128; off > 0; off >>= 1) {
    if (threadIdx.x < off) s[threadIdx.x] += s[threadIdx.x + off];
    __syncthreads();
  }
  if (threadIdx.x == 0) part[blockIdx.x] = s[0];
}

__global__ __launch_bounds__(1024) void scan_top_kernel(int* __restrict__ part, int P) {
  __shared__ int s[1024];
  int t = threadIdx.x;
  int v = (t < P) ? part[t] : 0;
  s[t] = v;
  __syncthreads();
  for (int off = 1; off < 1024; off <<= 1) {
    int x = s[t];
    int y = (t >= off) ? s[t - off] : 0;
    __syncthreads();
    s[t] = x + y;
    __syncthreads();
  }
  if (t < P) part[t] = s[t] - v;   // exclusive
}

__global__ void scan_apply_kernel(const int* __restrict__ cnt, const int* __restrict__ part,
                                  int* __restrict__ row_start, int n) {
  __shared__ int s[256];
  int base = part[blockIdx.x];
  int i = blockIdx.x * 256 + threadIdx.x;
  int v = (i < n) ? cnt[i] : 0;
  s[threadIdx.x] = v;
  __syncthreads();
  for (int off = 1; off < 256; off <<= 1) {
    int x = s[threadIdx.x];
    int y = (threadIdx.x >= off) ? s[threadIdx.x - off] : 0;
    __syncthreads();
    s[threadIdx.x] = x + y;
    __syncthreads();
  }
  if (i < n) row_start[i] = base + s[threadIdx.x] - v;
  if (i == n - 1) row_start[n] = base + s[threadIdx.x];
}

__global__ void scatter_kernel(const int* __restrict__ rows, const int* __restrict__ cols,
                               const void* __restrict__ vals, const int* __restrict__ fm_p,
                               const int* __restrict__ row_start, int* __restrict__ fill,
                               int2* __restrict__ ecv, int E) {
  int fm = *fm_p;
  int i = blockIdx.x * blockDim.x + threadIdx.x;
  int stride = gridDim.x * blockDim.x;
  for (; i < E; i += stride) {
    int r = rows[i];
    int pos = atomicAdd(&fill[r], 1);
    int idx = row_start[r] + pos;
    ecv[idx] = make_int2(cols[i], __float_as_int(read_f(vals, fm, i)));
  }
}

// ---------------- fused conversions ----------------
__global__ void split_w_all_kernel(const void* __restrict__ W1, const void* __restrict__ W2,
                                   const void* __restrict__ W3, const int* __restrict__ fm_p,
                                   ushort_t* __restrict__ whi, ushort_t* __restrict__ wlo,
                                   int n1, int n2, int n3) {
  int fm = *fm_p;
  int total = n1 + n2 + n3;
  int i = blockIdx.x * blockDim.x + threadIdx.x;
  int stride = gridDim.x * blockDim.x;
  for (; i < total; i += stride) {
    const void* src; int j;
    if (i < n1) { src = W1; j = i; }
    else if (i < n1 + n2) { src = W2; j = i - n1; }
    else { src = W3; j = i - n1 - n2; }
    float v = read_f(src, fm, j);
    ushort_t h = f2bf(v);
    whi[i] = h;
    wlo[i] = f2bf(v - bf2f(h));
  }
}

__global__ void cvt_bias_all_kernel(const void* __restrict__ b1, const void* __restrict__ b2,
                                    const void* __restrict__ b3, const int* __restrict__ fm_p,
                                    float* __restrict__ dst, int n1, int n2, int n3) {
  int fm = *fm_p;
  int i = threadIdx.x + blockIdx.x * blockDim.x;
  int total = n1 + n2 + n3;
  if (i >= total) return;
  const void* src; int j;
  if (i < n1) { src = b1; j = i; }
  else if (i < n1 + n2) { src = b2; j = i - n1; }
  else { src = b3; j = i - n1 - n2; }
  dst[i] = read_f(src, fm, j);
}

__global__ void cvt_bf16x4_kernel(const void* __restrict__ src, const int* __restrict__ fm_p,
                                  ushort_t* __restrict__ dst, int n4) {
  int fm = *fm_p;
  int i = blockIdx.x * blockDim.x + threadIdx.x;
  int stride = gridDim.x * blockDim.x;
  for (; i < n4; i += stride) {
    if (fm == 0) {
      f32x4 v = ((const f32x4*)src)[i];
      unsigned int lo = (unsigned int)f2bf(v[0]) | ((unsigned int)f2bf(v[1]) << 16);
      unsigned int hi = (unsigned int)f2bf(v[2]) | ((unsigned int)f2bf(v[3]) << 16);
      ((u32x2*)dst)[i] = (u32x2){lo, hi};
    } else {
      ((u32x2*)dst)[i] = ((const u32x2*)src)[i];
    }
  }
}

// ---------------- GEMM: W-in-registers + A-prefetch (r9, kept) --------------
// g[m,n] = sum_k A[m,k]*W[n,k] + bias[n].  K = KC*32, nct = Nout/16.
// Wave owns col-tile ct = gw % nct; W hi/lo frags resident; next row-tile's
// A-frags issued before the MFMA block. Layouts m89/m91-verified.
template<int KC>
__global__ __launch_bounds__(256) void gemm_breg_kernel(
    const ushort_t* __restrict__ A,
    const ushort_t* __restrict__ Whi, const ushort_t* __restrict__ Wlo,
    const float* __restrict__ bias, ushort_t* __restrict__ g, int ldg,
    int M, int nct) {
  const int K = KC * 32;
  int wave = threadIdx.x >> 6, lane = threadIdx.x & 63;
  int gw = blockIdx.x * 4 + wave;
  int NW = gridDim.x * 4;
  int mr = lane & 15, quad = lane >> 4;
  int ct = gw % nct;
  int nrt = (M + 15) >> 4;
  int ntasks = nct * nrt;
  if (gw >= ntasks) return;

  bf16x8 wh[KC], wl[KC];
  {
    const ushort_t* wp = Whi + (size_t)(ct * 16 + mr) * K + quad * 8;
    const ushort_t* wq = Wlo + (size_t)(ct * 16 + mr) * K + quad * 8;
#pragma unroll
    for (int kc = 0; kc < KC; ++kc) {
      wh[kc] = *(const bf16x8*)(wp + kc * 32);
      wl[kc] = *(const bf16x8*)(wq + kc * 32);
    }
  }
  int col = ct * 16 + mr;
  float bv = bias[col];

  int task = gw;
  bf16x8 af[KC];
  {
    int m = (task / nct) * 16 + mr; if (m >= M) m = M - 1;
    const ushort_t* ap = A + (size_t)m * K + quad * 8;
#pragma unroll
    for (int kc = 0; kc < KC; ++kc) af[kc] = *(const bf16x8*)(ap + kc * 32);
  }

#pragma unroll 1
  for (;;) {
    int next = task + NW;
    bool has_next = next < ntasks;
    bf16x8 afn[KC];
    if (has_next) {
      int m = (next / nct) * 16 + mr; if (m >= M) m = M - 1;
      const ushort_t* ap = A + (size_t)m * K + quad * 8;
#pragma unroll
      for (int kc = 0; kc < KC; ++kc) afn[kc] = *(const bf16x8*)(ap + kc * 32);
    }

    f32x4 acc[4];
#pragma unroll
    for (int t = 0; t < 4; ++t) acc[t] = (f32x4){0.f, 0.f, 0.f, 0.f};
#pragma unroll
    for (int kc = 0; kc < KC; ++kc) {
      acc[(2 * kc) & 3] = __builtin_amdgcn_mfma_f32_16x16x32_bf16(af[kc], wh[kc], acc[(2 * kc) & 3], 0, 0, 0);
      acc[(2 * kc + 1) & 3] = __builtin_amdgcn_mfma_f32_16x16x32_bf16(af[kc], wl[kc], acc[(2 * kc + 1) & 3], 0, 0, 0);
    }
    int m0 = (task / nct) * 16;
#pragma unroll
    for (int r = 0; r < 4; ++r) {
      int row = m0 + quad * 4 + r;
      float s = ((acc[0][r] + acc[1][r]) + (acc[2][r] + acc[3][r])) + bv;
      if (row < M) g[(size_t)row * ldg + col] = f2bf(s);
    }
    if (!has_next) break;
#pragma unroll
    for (int kc = 0; kc < KC; ++kc) af[kc] = afn[kc];
    task = next;
  }
}

// ---------------- SpMM v6: wide one-wave-per-row, 16-deep, packed edges -----
// out[r,f] = sum_e val[e]*G[col[e],f].  VEC elems/lane (64*VEC = D).
// 16 gathers in flight (tail clamped with val 0). Packed int2 edge stream.
// MODE 1: leaky(0.2)+mask -> bf16.  MODE 0: plain -> f32 (final out).
template<int MODE, int VEC>
__global__ __launch_bounds__(256) void spmm6_kernel(
    const int* __restrict__ row_start, const int2* __restrict__ ecv,
    const ushort_t* __restrict__ G, int D,
    const void* __restrict__ mask, const int* __restrict__ mmode_p,
    void* __restrict__ outp, int N) {
  const int DEPTH = 16;
  int wave = threadIdx.x >> 6, lane = threadIdx.x & 63;
  int r = blockIdx.x * 4 + wave;
  if (r >= N) return;
  int f0 = lane * VEC;
  int e = row_start[r], e1 = row_start[r + 1];
  float a[VEC];
#pragma unroll
  for (int q = 0; q < VEC; ++q) a[q] = 0.f;

  for (; e < e1; e += DEPTH) {
    int idx[DEPTH]; float v[DEPTH];
#pragma unroll
    for (int j = 0; j < DEPTH; ++j) {
      int ee = e + j;
      bool ok = ee < e1;
      int2 cv = ecv[ok ? ee : e1 - 1];
      idx[j] = cv.x;
      v[j] = ok ? __int_as_float(cv.y) : 0.f;
    }
    if (VEC == 4) {
      u32x2 gg[DEPTH];
#pragma unroll
      for (int j = 0; j < DEPTH; ++j)
        gg[j] = *(const u32x2*)(G + (size_t)idx[j] * D + f0);
#pragma unroll
      for (int j = 0; j < DEPTH; ++j) {
        a[0] += v[j] * bf2f((ushort_t)gg[j][0]);
        a[1] += v[j] * bf2f((ushort_t)(gg[j][0] >> 16));
        a[2] += v[j] * bf2f((ushort_t)gg[j][1]);
        a[3] += v[j] * bf2f((ushort_t)(gg[j][1] >> 16));
      }
    } else if (VEC == 2) {
      unsigned int gg[DEPTH];
#pragma unroll
      for (int j = 0; j < DEPTH; ++j)
        gg[j] = *(const unsigned int*)(G + (size_t)idx[j] * D + f0);
#pragma unroll
      for (int j = 0; j < DEPTH; ++j) {
        a[0] += v[j] * bf2f((ushort_t)gg[j]);
        a[1] += v[j] * bf2f((ushort_t)(gg[j] >> 16));
      }
    } else {
      ushort_t h[DEPTH];
#pragma unroll
      for (int j = 0; j < DEPTH; ++j) h[j] = G[(size_t)idx[j] * D + f0];
#pragma unroll
      for (int j = 0; j < DEPTH; ++j) a[0] += v[j] * bf2f(h[j]);
    }
  }

  size_t o = (size_t)r * D + f0;
  if (MODE == 1) {
    int mm = *mmode_p;
    ushort_t pk[VEC];
#pragma unroll
    for (int q = 0; q < VEC; ++q) {
      float t = a[q];
      t = (t >= 0.f) ? t : 0.2f * t;                     // leaky relu 0.2
      t = mask_keep(mask, mm, o + q) ? t * 1.25f : 0.f;  // keep = 1/(1-0.2)
      pk[q] = f2bf(t);
    }
    if (VEC == 4) {
      u32x2 w;
      w[0] = (unsigned int)pk[0] | ((unsigned int)pk[1] << 16);
      w[1] = (unsigned int)pk[2] | ((unsigned int)pk[3] << 16);
      *(u32x2*)((ushort_t*)outp + o) = w;
    } else if (VEC == 2) {
      *(unsigned int*)((ushort_t*)outp + o) =
          (unsigned int)pk[0] | ((unsigned int)pk[1] << 16);
    } else {
      ((ushort_t*)outp)[o] = pk[0];
    }
  } else {
#pragma unroll
    for (int q = 0; q < VEC; ++q) ((float*)outp)[o + q] = a[q];
  }
}

// ---------------- launch ----------------
extern "C" void kernel_launch(void* const* d_in, const int* in_sizes, int n_in,
                              void* d_out, int out_size, void* d_ws, size_t ws_size,
                              hipStream_t stream) {
  const void* x     = d_in[0];
  const int*  rows  = (const int*)d_in[1];
  const int*  cols  = (const int*)d_in[2];
  const void* vals  = d_in[3];
  const void* W1    = d_in[4];
  const void* b1    = d_in[5];
  const void* W2    = d_in[6];
  const void* b2    = d_in[7];
  const void* W3    = d_in[8];
  const void* b3    = d_in[9];
  const void* mask1 = d_in[10];
  const void* mask2 = d_in[11];

  const int H1  = in_sizes[5];            // 256
  const int H2  = in_sizes[7];            // 128
  const int OUT = in_sizes[9];            // 64
  const int IN  = in_sizes[4] / H1;       // 256
  const int N   = in_sizes[0] / IN;       // 50000
  const int E   = in_sizes[1];            // 800000
  const int W1n = in_sizes[4], W2n = in_sizes[6], W3n = in_sizes[8];

  char* ws = (char*)d_ws;
  size_t off = 0;
  auto alloc = [&](size_t bytes) -> void* {
    void* p = ws + off;
    off = (off + bytes + 255) & ~(size_t)255;
    return p;
  };
  int*      modes     = (int*)alloc(4 * 4);
  int*      row_start = (int*)alloc((size_t)(N + 1) * 4);
  int*      cnt       = (int*)alloc((size_t)N * 4);
  int*      part      = (int*)alloc(1024 * 4);
  int2*     ecv       = (int2*)alloc((size_t)E * 8);
  ushort_t* whi       = (ushort_t*)alloc((size_t)(W1n + W2n + W3n) * 2);
  ushort_t* wlo       = (ushort_t*)alloc((size_t)(W1n + W2n + W3n) * 2);
  float*    biasf     = (float*)alloc((size_t)(H1 + H2 + OUT) * 4);
  ushort_t* bufA      = (ushort_t*)alloc((size_t)N * H1 * 2);   // 25.6 MB
  ushort_t* bufB      = (ushort_t*)alloc((size_t)N * H1 * 2);   // 25.6 MB
  ushort_t* bufC      = (ushort_t*)alloc((size_t)N * H1 * 2);   // 25.6 MB
  // total ~84 MB (<=110 MB proven safe in r3)

  int* fmode = modes;
  int* mm1   = modes + 1;
  int* mm2   = modes + 2;
  ushort_t* w1hi = whi,             *w1lo = wlo;
  ushort_t* w2hi = whi + W1n,       *w2lo = wlo + W1n;
  ushort_t* w3hi = whi + W1n + W2n, *w3lo = wlo + W1n + W2n;

  sniff_all_kernel<<<3, 256, 0, stream>>>(x, mask1, mask2, modes);

  // CSR build with parallel scan
  const int P = (N + 255) / 256;
  hipMemsetAsync(cnt, 0, (size_t)N * 4, stream);
  hist_kernel<<<1024, 256, 0, stream>>>(rows, cnt, E);
  scan_part_kernel<<<P, 256, 0, stream>>>(cnt, part, N);
  scan_top_kernel<<<1, 1024, 0, stream>>>(part, P);
  scan_apply_kernel<<<P, 256, 0, stream>>>(cnt, part, row_start, N);
  hipMemsetAsync(cnt, 0, (size_t)N * 4, stream);
  scatter_kernel<<<1024, 256, 0, stream>>>(rows, cols, vals, fmode, row_start, cnt, ecv, E);

  // conversions (fused)
  int wtot = W1n + W2n + W3n;
  split_w_all_kernel<<<(wtot + 255) / 256, 256, 0, stream>>>(
      W1, W2, W3, fmode, whi, wlo, W1n, W2n, W3n);
  cvt_bias_all_kernel<<<(H1 + H2 + OUT + 255) / 256, 256, 0, stream>>>(
      b1, b2, b3, fmode, biasf, H1, H2, OUT);
  cvt_bf16x4_kernel<<<2048, 256, 0, stream>>>(x, fmode, bufA, (N * IN) / 4);

  const int GEMM_BLOCKS = 2048;            // 8192 waves; % {16,8,4} == 0
  int spmm_grid = (N + 3) / 4;

  // layer 1: GEMM(IN->H1) -> SpMM(D=256, VEC=4, act+mask1)
  gemm_breg_kernel<8><<<GEMM_BLOCKS, 256, 0, stream>>>(
      bufA, w1hi, w1lo, biasf, bufB, H1, N, H1 / 16);
  spmm6_kernel<1, 4><<<spmm_grid, 256, 0, stream>>>(
      row_start, ecv, bufB, H1, mask1, mm1, bufC, N);
  // layer 2: GEMM(H1->H2) -> SpMM(D=128, VEC=2, act+mask2)
  gemm_breg_kernel<8><<<GEMM_BLOCKS, 256, 0, stream>>>(
      bufC, w2hi, w2lo, biasf + H1, bufB, H2, N, H2 / 16);
  spmm6_kernel<1, 2><<<spmm_grid, 256, 0, stream>>>(
      row_start, ecv, bufB, H2, mask2, mm2, bufA, N);
  // layer 3: GEMM(H2->OUT) -> SpMM(D=64, VEC=1, plain) -> f32 d_out
  gemm_breg_kernel<4><<<GEMM_BLOCKS, 256, 0, stream>>>(
      bufA, w3hi, w3lo, biasf + H1 + H2, bufB, OUT, N, OUT / 16);
  spmm6_kernel<0, 1><<<spmm_grid, 256, 0, stream>>>(
      row_start, ecv, bufB, OUT, nullptr, fmode, d_out, N);
}

// Round 11
// 502.573 us; speedup vs baseline: 1.3357x; 1.1622x over previous
//
#include <hip/hip_runtime.h>

// ===========================================================================
// ViewGCNEncoder r11. Proven dtype model: f32 in / f32 out / bf16-graded,
// masks sniffed. r10->r11: SpMM DEPTH back to 8 (r10's 16-deep wasted ~45%
// of gather issues on clamp-dupes at mean degree 16), edge stream scalarized
// (readfirstlane -> s_load, frees VMEM pipe for gathers). GEMM + aux frozen.
// Workspace ~84 MB (<=110 MB proven safe in r3).
// ===========================================================================

typedef unsigned short ushort_t;
typedef __attribute__((ext_vector_type(8))) short bf16x8;   // 8 bf16 = 4 VGPRs
typedef __attribute__((ext_vector_type(4))) float f32x4;
typedef __attribute__((ext_vector_type(2))) unsigned int u32x2;

__device__ __forceinline__ float bf2f(ushort_t u) {
  return __uint_as_float(((unsigned int)u) << 16);
}
__device__ __forceinline__ ushort_t f2bf(float f) {
  unsigned int u = __float_as_uint(f);
  return (ushort_t)((u + 0x7FFFu + ((u >> 16) & 1u)) >> 16);  // RNE
}
__device__ __forceinline__ float read_f(const void* p, int fm, size_t i) {
  return fm ? bf2f(((const ushort_t*)p)[i]) : ((const float*)p)[i];
}

// ---------------- fused dtype sniff: block 0 = float(x), 1/2 = masks -------
__global__ void sniff_all_kernel(const void* __restrict__ x,
                                 const void* __restrict__ m1,
                                 const void* __restrict__ m2,
                                 int* __restrict__ modes) {
  if (blockIdx.x == 0) {
    __shared__ int bfok;
    if (threadIdx.x == 0) bfok = 1;
    __syncthreads();
    for (int i = threadIdx.x; i < 8192; i += blockDim.x) {
      ushort_t h = ((const ushort_t*)x)[i];
      int e = (h >> 7) & 0xFF;
      if (!(h == 0 || (e >= 95 && e <= 133))) atomicAnd(&bfok, 0);
    }
    __syncthreads();
    if (threadIdx.x == 0) modes[0] = bfok;   // 1=bf16, 0=f32
  } else {
    const void* p = (blockIdx.x == 1) ? m1 : m2;
    __shared__ int ok[4];  // [i32, f32, bf16, u8]
    if (threadIdx.x < 4) ok[threadIdx.x] = 1;
    __syncthreads();
    for (int i = threadIdx.x; i < 4096; i += blockDim.x) {
      unsigned int w = ((const unsigned int*)p)[i];
      if (!(w == 0u || w == 1u)) atomicAnd(&ok[0], 0);
      if (!(w == 0u || w == 0x3F800000u)) atomicAnd(&ok[1], 0);
      unsigned int h16 = w >> 16, l16 = w & 0xFFFFu;
      if (!((h16 == 0u || h16 == 0x3F80u) && (l16 == 0u || l16 == 0x3F80u)))
        atomicAnd(&ok[2], 0);
      if (((w | (w >> 8) | (w >> 16) | (w >> 24)) & 0xFEu) != 0u) atomicAnd(&ok[3], 0);
    }
    __syncthreads();
    if (threadIdx.x == 0)
      modes[blockIdx.x] = ok[0] ? 1 : (ok[1] ? 2 : (ok[2] ? 3 : 0));
  }
}

__device__ __forceinline__ bool mask_keep(const void* mask, int mm, size_t o) {
  switch (mm) {
    case 1:  return ((const int*)mask)[o] != 0;
    case 2:  return ((const unsigned int*)mask)[o] != 0u;
    case 3:  return ((const ushort_t*)mask)[o] != 0;
    default: return ((const unsigned char*)mask)[o] != 0;
  }
}

// ---------------- CSR build ----------------
__global__ void hist_kernel(const int* __restrict__ rows, int* __restrict__ cnt, int E) {
  int i = blockIdx.x * blockDim.x + threadIdx.x;
  int stride = gridDim.x * blockDim.x;
  for (; i < E; i += stride) atomicAdd(&cnt[rows[i]], 1);
}

__global__ void scan_part_kernel(const int* __restrict__ cnt, int* __restrict__ part, int n) {
  __shared__ int s[256];
  int i = blockIdx.x * 256 + threadIdx.x;
  s[threadIdx.x] = (i < n) ? cnt[i] : 0;
  __syncthreads();
  for (int off = 128; off > 0; off >>= 1) {
    if (threadIdx.x < off) s[threadIdx.x] += s[threadIdx.x + off];
    __syncthreads();
  }
  if (threadIdx.x == 0) part[blockIdx.x] = s[0];
}

__global__ __launch_bounds__(1024) void scan_top_kernel(int* __restrict__ part, int P) {
  __shared__ int s[1024];
  int t = threadIdx.x;
  int v = (t < P) ? part[t] : 0;
  s[t] = v;
  __syncthreads();
  for (int off = 1; off < 1024; off <<= 1) {
    int x = s[t];
    int y = (t >= off) ? s[t - off] : 0;
    __syncthreads();
    s[t] = x + y;
    __syncthreads();
  }
  if (t < P) part[t] = s[t] - v;   // exclusive
}

__global__ void scan_apply_kernel(const int* __restrict__ cnt, const int* __restrict__ part,
                                  int* __restrict__ row_start, int n) {
  __shared__ int s[256];
  int base = part[blockIdx.x];
  int i = blockIdx.x * 256 + threadIdx.x;
  int v = (i < n) ? cnt[i] : 0;
  s[threadIdx.x] = v;
  __syncthreads();
  for (int off = 1; off < 256; off <<= 1) {
    int x = s[threadIdx.x];
    int y = (threadIdx.x >= off) ? s[threadIdx.x - off] : 0;
    __syncthreads();
    s[threadIdx.x] = x + y;
    __syncthreads();
  }
  if (i < n) row_start[i] = base + s[threadIdx.x] - v;
  if (i == n - 1) row_start[n] = base + s[threadIdx.x];
}

__global__ void scatter_kernel(const int* __restrict__ rows, const int* __restrict__ cols,
                               const void* __restrict__ vals, const int* __restrict__ fm_p,
                               const int* __restrict__ row_start, int* __restrict__ fill,
                               int2* __restrict__ ecv, int E) {
  int fm = *fm_p;
  int i = blockIdx.x * blockDim.x + threadIdx.x;
  int stride = gridDim.x * blockDim.x;
  for (; i < E; i += stride) {
    int r = rows[i];
    int pos = atomicAdd(&fill[r], 1);
    int idx = row_start[r] + pos;
    ecv[idx] = make_int2(cols[i], __float_as_int(read_f(vals, fm, i)));
  }
}

// ---------------- fused conversions ----------------
__global__ void split_w_all_kernel(const void* __restrict__ W1, const void* __restrict__ W2,
                                   const void* __restrict__ W3, const int* __restrict__ fm_p,
                                   ushort_t* __restrict__ whi, ushort_t* __restrict__ wlo,
                                   int n1, int n2, int n3) {
  int fm = *fm_p;
  int total = n1 + n2 + n3;
  int i = blockIdx.x * blockDim.x + threadIdx.x;
  int stride = gridDim.x * blockDim.x;
  for (; i < total; i += stride) {
    const void* src; int j;
    if (i < n1) { src = W1; j = i; }
    else if (i < n1 + n2) { src = W2; j = i - n1; }
    else { src = W3; j = i - n1 - n2; }
    float v = read_f(src, fm, j);
    ushort_t h = f2bf(v);
    whi[i] = h;
    wlo[i] = f2bf(v - bf2f(h));
  }
}

__global__ void cvt_bias_all_kernel(const void* __restrict__ b1, const void* __restrict__ b2,
                                    const void* __restrict__ b3, const int* __restrict__ fm_p,
                                    float* __restrict__ dst, int n1, int n2, int n3) {
  int fm = *fm_p;
  int i = threadIdx.x + blockIdx.x * blockDim.x;
  int total = n1 + n2 + n3;
  if (i >= total) return;
  const void* src; int j;
  if (i < n1) { src = b1; j = i; }
  else if (i < n1 + n2) { src = b2; j = i - n1; }
  else { src = b3; j = i - n1 - n2; }
  dst[i] = read_f(src, fm, j);
}

__global__ void cvt_bf16x4_kernel(const void* __restrict__ src, const int* __restrict__ fm_p,
                                  ushort_t* __restrict__ dst, int n4) {
  int fm = *fm_p;
  int i = blockIdx.x * blockDim.x + threadIdx.x;
  int stride = gridDim.x * blockDim.x;
  for (; i < n4; i += stride) {
    if (fm == 0) {
      f32x4 v = ((const f32x4*)src)[i];
      unsigned int lo = (unsigned int)f2bf(v[0]) | ((unsigned int)f2bf(v[1]) << 16);
      unsigned int hi = (unsigned int)f2bf(v[2]) | ((unsigned int)f2bf(v[3]) << 16);
      ((u32x2*)dst)[i] = (u32x2){lo, hi};
    } else {
      ((u32x2*)dst)[i] = ((const u32x2*)src)[i];
    }
  }
}

// ---------------- GEMM: W-in-registers + A-prefetch (r9/r10, frozen) --------
template<int KC>
__global__ __launch_bounds__(256) void gemm_breg_kernel(
    const ushort_t* __restrict__ A,
    const ushort_t* __restrict__ Whi, const ushort_t* __restrict__ Wlo,
    const float* __restrict__ bias, ushort_t* __restrict__ g, int ldg,
    int M, int nct) {
  const int K = KC * 32;
  int wave = threadIdx.x >> 6, lane = threadIdx.x & 63;
  int gw = blockIdx.x * 4 + wave;
  int NW = gridDim.x * 4;
  int mr = lane & 15, quad = lane >> 4;
  int ct = gw % nct;
  int nrt = (M + 15) >> 4;
  int ntasks = nct * nrt;
  if (gw >= ntasks) return;

  bf16x8 wh[KC], wl[KC];
  {
    const ushort_t* wp = Whi + (size_t)(ct * 16 + mr) * K + quad * 8;
    const ushort_t* wq = Wlo + (size_t)(ct * 16 + mr) * K + quad * 8;
#pragma unroll
    for (int kc = 0; kc < KC; ++kc) {
      wh[kc] = *(const bf16x8*)(wp + kc * 32);
      wl[kc] = *(const bf16x8*)(wq + kc * 32);
    }
  }
  int col = ct * 16 + mr;
  float bv = bias[col];

  int task = gw;
  bf16x8 af[KC];
  {
    int m = (task / nct) * 16 + mr; if (m >= M) m = M - 1;
    const ushort_t* ap = A + (size_t)m * K + quad * 8;
#pragma unroll
    for (int kc = 0; kc < KC; ++kc) af[kc] = *(const bf16x8*)(ap + kc * 32);
  }

#pragma unroll 1
  for (;;) {
    int next = task + NW;
    bool has_next = next < ntasks;
    bf16x8 afn[KC];
    if (has_next) {
      int m = (next / nct) * 16 + mr; if (m >= M) m = M - 1;
      const ushort_t* ap = A + (size_t)m * K + quad * 8;
#pragma unroll
      for (int kc = 0; kc < KC; ++kc) afn[kc] = *(const bf16x8*)(ap + kc * 32);
    }

    f32x4 acc[4];
#pragma unroll
    for (int t = 0; t < 4; ++t) acc[t] = (f32x4){0.f, 0.f, 0.f, 0.f};
#pragma unroll
    for (int kc = 0; kc < KC; ++kc) {
      acc[(2 * kc) & 3] = __builtin_amdgcn_mfma_f32_16x16x32_bf16(af[kc], wh[kc], acc[(2 * kc) & 3], 0, 0, 0);
      acc[(2 * kc + 1) & 3] = __builtin_amdgcn_mfma_f32_16x16x32_bf16(af[kc], wl[kc], acc[(2 * kc + 1) & 3], 0, 0, 0);
    }
    int m0 = (task / nct) * 16;
#pragma unroll
    for (int r = 0; r < 4; ++r) {
      int row = m0 + quad * 4 + r;
      float s = ((acc[0][r] + acc[1][r]) + (acc[2][r] + acc[3][r])) + bv;
      if (row < M) g[(size_t)row * ldg + col] = f2bf(s);
    }
    if (!has_next) break;
#pragma unroll
    for (int kc = 0; kc < KC; ++kc) af[kc] = afn[kc];
    task = next;
  }
}

// ---------------- SpMM v7: depth 8, scalarized edge stream ------------------
// out[r,f] = sum_e val[e]*G[col[e],f].  One wave per row, VEC elems/lane.
// e/e1/ecv batches are wave-uniform -> readfirstlane forces SGPR + s_load
// (contiguous 64B batch -> mergeable), VMEM pipe carries only gathers.
// Main loop: full 8-batches; one clamped tail batch.
// MODE 1: leaky(0.2)+mask -> bf16.  MODE 0: plain -> f32 (final out).
template<int MODE, int VEC>
__global__ __launch_bounds__(256) void spmm7_kernel(
    const int* __restrict__ row_start, const int2* __restrict__ ecv,
    const ushort_t* __restrict__ G, int D,
    const void* __restrict__ mask, const int* __restrict__ mmode_p,
    void* __restrict__ outp, int N) {
  int wave = threadIdx.x >> 6, lane = threadIdx.x & 63;
  int r = blockIdx.x * 4 + wave;
  if (r >= N) return;
  int f0 = lane * VEC;
  int e  = __builtin_amdgcn_readfirstlane(row_start[r]);
  int e1 = __builtin_amdgcn_readfirstlane(row_start[r + 1]);
  float a[VEC];
#pragma unroll
  for (int q = 0; q < VEC; ++q) a[q] = 0.f;

  // main: full batches of 8 (contiguous scalar-loadable edge block)
  for (; e + 8 <= e1; e += 8) {
    int2 cv[8];
#pragma unroll
    for (int j = 0; j < 8; ++j) cv[j] = ecv[e + j];
    if (VEC == 4) {
      u32x2 gg[8];
#pragma unroll
      for (int j = 0; j < 8; ++j)
        gg[j] = *(const u32x2*)(G + (size_t)cv[j].x * D + f0);
#pragma unroll
      for (int j = 0; j < 8; ++j) {
        float v = __int_as_float(cv[j].y);
        a[0] += v * bf2f((ushort_t)gg[j][0]);
        a[1] += v * bf2f((ushort_t)(gg[j][0] >> 16));
        a[2] += v * bf2f((ushort_t)gg[j][1]);
        a[3] += v * bf2f((ushort_t)(gg[j][1] >> 16));
      }
    } else if (VEC == 2) {
      unsigned int gg[8];
#pragma unroll
      for (int j = 0; j < 8; ++j)
        gg[j] = *(const unsigned int*)(G + (size_t)cv[j].x * D + f0);
#pragma unroll
      for (int j = 0; j < 8; ++j) {
        float v = __int_as_float(cv[j].y);
        a[0] += v * bf2f((ushort_t)gg[j]);
        a[1] += v * bf2f((ushort_t)(gg[j] >> 16));
      }
    } else {
      ushort_t h[8];
#pragma unroll
      for (int j = 0; j < 8; ++j) h[j] = G[(size_t)cv[j].x * D + f0];
#pragma unroll
      for (int j = 0; j < 8; ++j) a[0] += __int_as_float(cv[j].y) * bf2f(h[j]);
    }
  }
  // tail: one clamped batch (<=7 real edges, dupes carry v=0)
  if (e < e1) {
    int idx[8]; float v[8];
#pragma unroll
    for (int j = 0; j < 8; ++j) {
      int ee = e + j;
      bool ok = ee < e1;
      int2 cv = ecv[ok ? ee : e1 - 1];
      idx[j] = cv.x;
      v[j] = ok ? __int_as_float(cv.y) : 0.f;
    }
    if (VEC == 4) {
      u32x2 gg[8];
#pragma unroll
      for (int j = 0; j < 8; ++j)
        gg[j] = *(const u32x2*)(G + (size_t)idx[j] * D + f0);
#pragma unroll
      for (int j = 0; j < 8; ++j) {
        a[0] += v[j] * bf2f((ushort_t)gg[j][0]);
        a[1] += v[j] * bf2f((ushort_t)(gg[j][0] >> 16));
        a[2] += v[j] * bf2f((ushort_t)gg[j][1]);
        a[3] += v[j] * bf2f((ushort_t)(gg[j][1] >> 16));
      }
    } else if (VEC == 2) {
      unsigned int gg[8];
#pragma unroll
      for (int j = 0; j < 8; ++j)
        gg[j] = *(const unsigned int*)(G + (size_t)idx[j] * D + f0);
#pragma unroll
      for (int j = 0; j < 8; ++j) {
        a[0] += v[j] * bf2f((ushort_t)gg[j]);
        a[1] += v[j] * bf2f((ushort_t)(gg[j] >> 16));
      }
    } else {
      ushort_t h[8];
#pragma unroll
      for (int j = 0; j < 8; ++j) h[j] = G[(size_t)idx[j] * D + f0];
#pragma unroll
      for (int j = 0; j < 8; ++j) a[0] += v[j] * bf2f(h[j]);
    }
  }

  size_t o = (size_t)r * D + f0;
  if (MODE == 1) {
    int mm = *mmode_p;
    ushort_t pk[VEC];
#pragma unroll
    for (int q = 0; q < VEC; ++q) {
      float t = a[q];
      t = (t >= 0.f) ? t : 0.2f * t;                     // leaky relu 0.2
      t = mask_keep(mask, mm, o + q) ? t * 1.25f : 0.f;  // keep = 1/(1-0.2)
      pk[q] = f2bf(t);
    }
    if (VEC == 4) {
      u32x2 w;
      w[0] = (unsigned int)pk[0] | ((unsigned int)pk[1] << 16);
      w[1] = (unsigned int)pk[2] | ((unsigned int)pk[3] << 16);
      *(u32x2*)((ushort_t*)outp + o) = w;
    } else if (VEC == 2) {
      *(unsigned int*)((ushort_t*)outp + o) =
          (unsigned int)pk[0] | ((unsigned int)pk[1] << 16);
    } else {
      ((ushort_t*)outp)[o] = pk[0];
    }
  } else {
#pragma unroll
    for (int q = 0; q < VEC; ++q) ((float*)outp)[o + q] = a[q];
  }
}

// ---------------- launch ----------------
extern "C" void kernel_launch(void* const* d_in, const int* in_sizes, int n_in,
                              void* d_out, int out_size, void* d_ws, size_t ws_size,
                              hipStream_t stream) {
  const void* x     = d_in[0];
  const int*  rows  = (const int*)d_in[1];
  const int*  cols  = (const int*)d_in[2];
  const void* vals  = d_in[3];
  const void* W1    = d_in[4];
  const void* b1    = d_in[5];
  const void* W2    = d_in[6];
  const void* b2    = d_in[7];
  const void* W3    = d_in[8];
  const void* b3    = d_in[9];
  const void* mask1 = d_in[10];
  const void* mask2 = d_in[11];

  const int H1  = in_sizes[5];            // 256
  const int H2  = in_sizes[7];            // 128
  const int OUT = in_sizes[9];            // 64
  const int IN  = in_sizes[4] / H1;       // 256
  const int N   = in_sizes[0] / IN;       // 50000
  const int E   = in_sizes[1];            // 800000
  const int W1n = in_sizes[4], W2n = in_sizes[6], W3n = in_sizes[8];

  char* ws = (char*)d_ws;
  size_t off = 0;
  auto alloc = [&](size_t bytes) -> void* {
    void* p = ws + off;
    off = (off + bytes + 255) & ~(size_t)255;
    return p;
  };
  int*      modes     = (int*)alloc(4 * 4);
  int*      row_start = (int*)alloc((size_t)(N + 1) * 4);
  int*      cnt       = (int*)alloc((size_t)N * 4);
  int*      part      = (int*)alloc(1024 * 4);
  int2*     ecv       = (int2*)alloc((size_t)E * 8);
  ushort_t* whi       = (ushort_t*)alloc((size_t)(W1n + W2n + W3n) * 2);
  ushort_t* wlo       = (ushort_t*)alloc((size_t)(W1n + W2n + W3n) * 2);
  float*    biasf     = (float*)alloc((size_t)(H1 + H2 + OUT) * 4);
  ushort_t* bufA      = (ushort_t*)alloc((size_t)N * H1 * 2);   // 25.6 MB
  ushort_t* bufB      = (ushort_t*)alloc((size_t)N * H1 * 2);   // 25.6 MB
  ushort_t* bufC      = (ushort_t*)alloc((size_t)N * H1 * 2);   // 25.6 MB
  // total ~84 MB (<=110 MB proven safe in r3)

  int* fmode = modes;
  int* mm1   = modes + 1;
  int* mm2   = modes + 2;
  ushort_t* w1hi = whi,             *w1lo = wlo;
  ushort_t* w2hi = whi + W1n,       *w2lo = wlo + W1n;
  ushort_t* w3hi = whi + W1n + W2n, *w3lo = wlo + W1n + W2n;

  sniff_all_kernel<<<3, 256, 0, stream>>>(x, mask1, mask2, modes);

  // CSR build with parallel scan
  const int P = (N + 255) / 256;
  hipMemsetAsync(cnt, 0, (size_t)N * 4, stream);
  hist_kernel<<<1024, 256, 0, stream>>>(rows, cnt, E);
  scan_part_kernel<<<P, 256, 0, stream>>>(cnt, part, N);
  scan_top_kernel<<<1, 1024, 0, stream>>>(part, P);
  scan_apply_kernel<<<P, 256, 0, stream>>>(cnt, part, row_start, N);
  hipMemsetAsync(cnt, 0, (size_t)N * 4, stream);
  scatter_kernel<<<1024, 256, 0, stream>>>(rows, cols, vals, fmode, row_start, cnt, ecv, E);

  // conversions (fused)
  int wtot = W1n + W2n + W3n;
  split_w_all_kernel<<<(wtot + 255) / 256, 256, 0, stream>>>(
      W1, W2, W3, fmode, whi, wlo, W1n, W2n, W3n);
  cvt_bias_all_kernel<<<(H1 + H2 + OUT + 255) / 256, 256, 0, stream>>>(
      b1, b2, b3, fmode, biasf, H1, H2, OUT);
  cvt_bf16x4_kernel<<<2048, 256, 0, stream>>>(x, fmode, bufA, (N * IN) / 4);

  const int GEMM_BLOCKS = 2048;            // 8192 waves; % {16,8,4} == 0
  int spmm_grid = (N + 3) / 4;

  // layer 1: GEMM(IN->H1) -> SpMM(D=256, VEC=4, act+mask1)
  gemm_breg_kernel<8><<<GEMM_BLOCKS, 256, 0, stream>>>(
      bufA, w1hi, w1lo, biasf, bufB, H1, N, H1 / 16);
  spmm7_kernel<1, 4><<<spmm_grid, 256, 0, stream>>>(
      row_start, ecv, bufB, H1, mask1, mm1, bufC, N);
  // layer 2: GEMM(H1->H2) -> SpMM(D=128, VEC=2, act+mask2)
  gemm_breg_kernel<8><<<GEMM_BLOCKS, 256, 0, stream>>>(
      bufC, w2hi, w2lo, biasf + H1, bufB, H2, N, H2 / 16);
  spmm7_kernel<1, 2><<<spmm_grid, 256, 0, stream>>>(
      row_start, ecv, bufB, H2, mask2, mm2, bufA, N);
  // layer 3: GEMM(H2->OUT) -> SpMM(D=64, VEC=1, plain) -> f32 d_out
  gemm_breg_kernel<4><<<GEMM_BLOCKS, 256, 0, stream>>>(
      bufA, w3hi, w3lo, biasf + H1 + H2, bufB, OUT, N, OUT / 16);
  spmm7_kernel<0, 1><<<spmm_grid, 256, 0, stream>>>(
      row_start, ecv, bufB, OUT, nullptr, fmode, d_out, N);
}